// Round 11
// baseline (1342.619 us; speedup 1.0000x reference)
//
#include <hip/hip_runtime.h>

#define N_IND 100000
#define N_COM 100000
#define N_TRU 100000
#define NTOT  300000
#define NEDGE 4800000
#define HDIM  64
#define CHUNK 8192
#define NCHUNKS 586   // ceil(NEDGE/CHUNK)
#define NCB 293       // ceil(NTOT/1024) coarse buckets of 1024 nodes
#define PADW 33       // 32 cols + 1 pad (encoder epilogue)

typedef float v4f __attribute__((ext_vector_type(4)));
typedef unsigned short v4u __attribute__((ext_vector_type(4)));  // clang vector: ok for nontemporal builtins

static __device__ __forceinline__ float elem4(const float4 v, int j) {
  return j == 0 ? v.x : j == 1 ? v.y : j == 2 ? v.z : v.w;
}

// fp32 -> bf16 round-to-nearest-even
static __device__ __forceinline__ unsigned short f2bf(float f) {
  unsigned u = __float_as_uint(f);
  unsigned r = (u + 0x7FFFu + ((u >> 16) & 1u)) >> 16;
  return (unsigned short)r;
}
static __device__ __forceinline__ float bf2f(unsigned short h) {
  return __uint_as_float(((unsigned)h) << 16);
}

// Coalesced bf16 epilogue for encoder (256 rows, 2 stages of 32 cols).
static __device__ __forceinline__ void store_rows_bf16(
    unsigned short* __restrict__ out, float* __restrict__ st, const float* acc,
    int node0, int rows, int tid, bool active) {
#pragma unroll
  for (int stage = 0; stage < 2; ++stage) {
    __syncthreads();
    if (active) {
#pragma unroll
      for (int j = 0; j < 32; ++j) st[tid * PADW + j] = acc[stage * 32 + j];
    }
    __syncthreads();
#pragma unroll
    for (int it = 0; it < 8; ++it) {
      int e = it * 256 + tid;
      int r = e >> 3;
      int c = (e & 7) * 4;
      if (r < rows) {
        v4u o;
        o.x = f2bf(st[r * PADW + c + 0]);
        o.y = f2bf(st[r * PADW + c + 1]);
        o.z = f2bf(st[r * PADW + c + 2]);
        o.w = f2bf(st[r * PADW + c + 3]);
        *(v4u*)(out + (size_t)(node0 + r) * HDIM + stage * 32 + c) = o;
      }
    }
  }
}

// ---------------- encoder: xb[base+n] = bf16(x[n] @ W + b) ----------------
template <int K>
__global__ __launch_bounds__(256, 2) void encode_kernel(
    const float* __restrict__ xin, const float* __restrict__ W,
    const float* __restrict__ b, unsigned short* __restrict__ xbout, int n, int base) {
  __shared__ float st[256 * PADW];
  int tid = threadIdx.x;
  int node0 = blockIdx.x * 256;
  int node = node0 + tid;
  bool active = node < n;
  int rows = min(256, n - node0);
  float acc[HDIM];
  if (active) {
    float4 row[K / 4];
    const float4* xv = (const float4*)(xin + (size_t)node * K);
#pragma unroll
    for (int i = 0; i < K / 4; ++i) row[i] = xv[i];
#pragma unroll
    for (int f = 0; f < HDIM; ++f) acc[f] = b[f];  // uniform -> s_load
#pragma unroll
    for (int k4 = 0; k4 < K / 4; ++k4) {
#pragma unroll
      for (int j = 0; j < 4; ++j) {
        float xs = elem4(row[k4], j);
        int k = k4 * 4 + j;
#pragma unroll
        for (int f = 0; f < HDIM; ++f) acc[f] += xs * W[k * HDIM + f];
      }
    }
  }
  store_rows_bf16(xbout + (size_t)base * HDIM, st, acc, node0, rows, tid, active);
}

// ---------------- coarse histogram: LDS-aggregated, 293 bins ----------------
__global__ __launch_bounds__(256) void coarse_hist_kernel(const int* __restrict__ dst,
                                                          int* __restrict__ chist, int e) {
  __shared__ int h[NCB];
  int tid = threadIdx.x;
  int start = blockIdx.x * CHUNK;
  int len = min(CHUNK, e - start);
  for (int i = tid; i < NCB; i += 256) h[i] = 0;
  __syncthreads();
  for (int i = tid; i < len; i += 256) atomicAdd(&h[dst[start + i] >> 10], 1);
  __syncthreads();
  for (int b = tid; b < NCB; b += 256) {
    int c = h[b];
    if (c > 0) atomicAdd(&chist[b], c);
  }
}

// ---------------- exclusive scan of 293 coarse counts ----------------
__global__ __launch_bounds__(512) void coarse_scan_kernel(const int* __restrict__ chist,
                                                          int* __restrict__ cbase,
                                                          int* __restrict__ ccur) {
  __shared__ int sv[512];
  int t = threadIdx.x;
  sv[t] = (t < NCB) ? chist[t] : 0;
  __syncthreads();
  for (int o = 1; o < 512; o <<= 1) {
    int y = (t >= o) ? sv[t - o] : 0;
    __syncthreads();
    sv[t] += y;
    __syncthreads();
  }
  if (t < NCB) {
    int ex = (t == 0) ? 0 : sv[t - 1];
    cbase[t] = ex;
    ccur[t] = ex;
  }
}

// ---------------- coarse scatter: block-aggregated reservation, dense runs ----------------
// packed word = (src << 10) | (dst & 1023); src < 2^19 -> 29 bits.
__global__ __launch_bounds__(256) void coarse_scatter_kernel(
    const int* __restrict__ src, const int* __restrict__ dst,
    int* __restrict__ ccur, unsigned* __restrict__ packed, int e) {
  __shared__ int h[NCB];
  __shared__ int lbase[NCB];
  int tid = threadIdx.x;
  int start = blockIdx.x * CHUNK;
  int len = min(CHUNK, e - start);
  for (int i = tid; i < NCB; i += 256) h[i] = 0;
  __syncthreads();
  for (int i = tid; i < len; i += 256) atomicAdd(&h[dst[start + i] >> 10], 1);
  __syncthreads();
  for (int b = tid; b < NCB; b += 256) {
    int c = h[b];
    lbase[b] = (c > 0) ? atomicAdd(&ccur[b], c) : 0;  // reserve contiguous run
  }
  __syncthreads();
  for (int i = tid; i < NCB; i += 256) h[i] = 0;  // reuse as rank counters
  __syncthreads();
  for (int i = tid; i < len; i += 256) {
    int d = dst[start + i];
    int s = src[start + i];
    int b = d >> 10;
    int r = atomicAdd(&h[b], 1);
    packed[lbase[b] + r] = ((unsigned)s << 10) | (unsigned)(d & 1023);
  }
}

// ---------------- per-coarse-bucket counting sort -> node-grouped CSR ----------------
__global__ __launch_bounds__(256) void sort_coarse_kernel(
    const unsigned* __restrict__ packed, const int* __restrict__ cbase,
    const int* __restrict__ chist, int* __restrict__ eidx,
    int* __restrict__ nodeoff, int* __restrict__ deg) {
  __shared__ int cnts[1024];
  __shared__ int cur[1024];
  __shared__ int part[256];
  int cb = blockIdx.x;
  int tid = threadIdx.x;
  for (int i = tid; i < 1024; i += 256) cnts[i] = 0;
  __syncthreads();
  int base = cbase[cb];
  int cnt = chist[cb];
  for (int i = tid; i < cnt; i += 256)
    atomicAdd(&cnts[packed[base + i] & 1023u], 1);
  __syncthreads();
  int c0 = cnts[4 * tid + 0], c1 = cnts[4 * tid + 1];
  int c2 = cnts[4 * tid + 2], c3 = cnts[4 * tid + 3];
  part[tid] = c0 + c1 + c2 + c3;
  __syncthreads();
  for (int o = 1; o < 256; o <<= 1) {
    int y = (tid >= o) ? part[tid - o] : 0;
    __syncthreads();
    part[tid] += y;
    __syncthreads();
  }
  int pre = (tid == 0) ? 0 : part[tid - 1];
  int e0 = pre, e1 = e0 + c0, e2 = e1 + c1, e3 = e2 + c2;
  cur[4 * tid + 0] = e0; cur[4 * tid + 1] = e1;
  cur[4 * tid + 2] = e2; cur[4 * tid + 3] = e3;
  int nodebase = (cb << 10) + 4 * tid;
  if (nodebase + 0 < NTOT) { deg[nodebase + 0] = c0; nodeoff[nodebase + 0] = base + e0; }
  if (nodebase + 1 < NTOT) { deg[nodebase + 1] = c1; nodeoff[nodebase + 1] = base + e1; }
  if (nodebase + 2 < NTOT) { deg[nodebase + 2] = c2; nodeoff[nodebase + 2] = base + e2; }
  if (nodebase + 3 < NTOT) { deg[nodebase + 3] = c3; nodeoff[nodebase + 3] = base + e3; }
  __syncthreads();
  for (int i = tid; i < cnt; i += 256) {
    unsigned pr = packed[base + i];
    int dl = (int)(pr & 1023u);
    int r = atomicAdd(&cur[dl], 1);
    eidx[base + r] = (int)(pr >> 10);  // 64 KB region exclusive to this block
  }
}

// ---------------- mean aggregation: bf16 in, bf16 out, 16 lanes/node ----------------
__global__ __launch_bounds__(256) void aggregate_kernel(
    const unsigned short* __restrict__ xb, const int* __restrict__ off,
    const int* __restrict__ deg, const int* __restrict__ eidx,
    unsigned short* __restrict__ meanb, int n) {
  int tid = blockIdx.x * 256 + threadIdx.x;
  int node = tid >> 4;
  int lane = tid & 15;
  if (node >= n) return;
  int start = off[node];
  int d = deg[node];
  const v4u* xv = (const v4u*)xb;   // row = 16 x v4u (128 B)
  float4 a0 = make_float4(0.f, 0.f, 0.f, 0.f);
  float4 a1 = make_float4(0.f, 0.f, 0.f, 0.f);
  float4 a2 = make_float4(0.f, 0.f, 0.f, 0.f);
  float4 a3 = make_float4(0.f, 0.f, 0.f, 0.f);
  int i = 0;
  for (; i + 4 <= d; i += 4) {
    int s0 = eidx[start + i + 0];
    int s1 = eidx[start + i + 1];
    int s2 = eidx[start + i + 2];
    int s3 = eidx[start + i + 3];
    v4u v0 = xv[(size_t)s0 * 16 + lane];
    v4u v1 = xv[(size_t)s1 * 16 + lane];
    v4u v2 = xv[(size_t)s2 * 16 + lane];
    v4u v3 = xv[(size_t)s3 * 16 + lane];
    a0.x += bf2f(v0.x); a0.y += bf2f(v0.y); a0.z += bf2f(v0.z); a0.w += bf2f(v0.w);
    a1.x += bf2f(v1.x); a1.y += bf2f(v1.y); a1.z += bf2f(v1.z); a1.w += bf2f(v1.w);
    a2.x += bf2f(v2.x); a2.y += bf2f(v2.y); a2.z += bf2f(v2.z); a2.w += bf2f(v2.w);
    a3.x += bf2f(v3.x); a3.y += bf2f(v3.y); a3.z += bf2f(v3.z); a3.w += bf2f(v3.w);
  }
  for (; i < d; ++i) {
    int s = eidx[start + i];
    v4u v = xv[(size_t)s * 16 + lane];
    a0.x += bf2f(v.x); a0.y += bf2f(v.y); a0.z += bf2f(v.z); a0.w += bf2f(v.w);
  }
  float inv = 1.0f / (float)(d > 0 ? d : 1);
  v4u o;
  o.x = f2bf((a0.x + a1.x + a2.x + a3.x) * inv);
  o.y = f2bf((a0.y + a1.y + a2.y + a3.y) * inv);
  o.z = f2bf((a0.z + a1.z + a2.z + a3.z) * inv);
  o.w = f2bf((a0.w + a1.w + a2.w + a3.w) * inv);
  // mean is a pure stream (read once by combine): keep it out of L3
  __builtin_nontemporal_store(o, (v4u*)meanb + (size_t)node * 16 + lane);
}

// ---------------- combine: relu(mean@Wl + x@Wr + b); 2 threads/node ----------------
// Output split across wave pairs: waves 0-1 compute cols 0..31, waves 2-3 cols 32..63
// for the same 128 nodes. half is wave-uniform -> weight reads stay s_load; acc[32]
// keeps VGPR demand ~60 so (256,4) reaches 4 blocks/CU without spills.
__global__ __launch_bounds__(256, 4) void combine_kernel(
    const unsigned short* __restrict__ meanb, const unsigned short* __restrict__ xb,
    const float* __restrict__ Wl, const float* __restrict__ Wr,
    const float* __restrict__ bb, float* __restrict__ outf,
    unsigned short* __restrict__ outb, int n) {
  __shared__ float st[128 * 65];
  int tid = threadIdx.x;
  int half = tid >> 7;            // wave-uniform
  int nl = tid & 127;
  int node0 = blockIdx.x * 128;
  int node = node0 + nl;
  bool active = node < n;
  int rows = min(128, n - node0);
  float acc[32];
  if (active) {
    const float* Wlh = Wl + half * 32;   // wave-uniform pointer
    const float* Wrh = Wr + half * 32;
#pragma unroll
    for (int f = 0; f < 32; ++f) acc[f] = bb[half * 32 + f];
    // phase 1: mean(bf16) @ Wl — process row in 4-chunk bursts (line-dense loads)
    const v4u* mv = (const v4u*)(meanb + (size_t)node * HDIM);
#pragma unroll
    for (int c = 0; c < 4; ++c) {
      v4u hh[4];
#pragma unroll
      for (int q = 0; q < 4; ++q) hh[q] = __builtin_nontemporal_load(mv + c * 4 + q);
#pragma unroll
      for (int q = 0; q < 4; ++q) {
        float m0 = bf2f(hh[q].x), m1 = bf2f(hh[q].y), m2 = bf2f(hh[q].z), m3 = bf2f(hh[q].w);
        int k = c * 16 + q * 4;
#pragma unroll
        for (int f = 0; f < 32; ++f)
          acc[f] += m0 * Wlh[(k + 0) * HDIM + f] + m1 * Wlh[(k + 1) * HDIM + f]
                  + m2 * Wlh[(k + 2) * HDIM + f] + m3 * Wlh[(k + 3) * HDIM + f];
      }
    }
    // phase 2: x(bf16) @ Wr
    const v4u* xv = (const v4u*)(xb + (size_t)node * HDIM);
#pragma unroll
    for (int c = 0; c < 4; ++c) {
      v4u hh[4];
#pragma unroll
      for (int q = 0; q < 4; ++q) hh[q] = xv[c * 4 + q];
#pragma unroll
      for (int q = 0; q < 4; ++q) {
        float m0 = bf2f(hh[q].x), m1 = bf2f(hh[q].y), m2 = bf2f(hh[q].z), m3 = bf2f(hh[q].w);
        int k = c * 16 + q * 4;
#pragma unroll
        for (int f = 0; f < 32; ++f)
          acc[f] += m0 * Wrh[(k + 0) * HDIM + f] + m1 * Wrh[(k + 1) * HDIM + f]
                  + m2 * Wrh[(k + 2) * HDIM + f] + m3 * Wrh[(k + 3) * HDIM + f];
      }
    }
#pragma unroll
    for (int f = 0; f < 32; ++f) acc[f] = fmaxf(acc[f], 0.f);
    // stage to LDS (pad 65: <=2-way bank alias, free)
#pragma unroll
    for (int j = 0; j < 32; ++j) st[nl * 65 + half * 32 + j] = acc[j];
  }
  __syncthreads();
  // coalesced copy-out: 128 rows x 64 cols, line-complete stores
#pragma unroll
  for (int it = 0; it < 8; ++it) {
    int e = it * 256 + tid;     // float4 index; 16 per row
    int r = e >> 4;
    int c = (e & 15) * 4;
    if (r < rows) {
      const float* ap = &st[r * 65 + c];
      if (outb) {
        v4u o;
        o.x = f2bf(ap[0]); o.y = f2bf(ap[1]); o.z = f2bf(ap[2]); o.w = f2bf(ap[3]);
        *(v4u*)(outb + (size_t)(node0 + r) * HDIM + c) = o;
      } else {
        float4 o;
        o.x = ap[0]; o.y = ap[1]; o.z = ap[2]; o.w = ap[3];
        *(float4*)(outf + (size_t)(node0 + r) * HDIM + c) = o;
      }
    }
  }
}

// ---------------- classifier: out = relu(x@Wc1+bc1)@Wc2 + bc2  (fp32 input) ----------------
__global__ __launch_bounds__(256, 2) void classifier_kernel(
    const float* __restrict__ x, const float* __restrict__ W1, const float* __restrict__ b1,
    const float* __restrict__ W2, const float* __restrict__ b2,
    float* __restrict__ out, int n) {
  int node = blockIdx.x * 256 + threadIdx.x;
  if (node >= n) return;
  float4 row[16];
  const float4* xv = (const float4*)(x + (size_t)node * HDIM);
#pragma unroll
  for (int i = 0; i < 16; ++i) row[i] = xv[i];
  float h[32];
#pragma unroll
  for (int f = 0; f < 32; ++f) h[f] = b1[f];
#pragma unroll
  for (int k4 = 0; k4 < 16; ++k4) {
#pragma unroll
    for (int j = 0; j < 4; ++j) {
      float xs = elem4(row[k4], j);
      int k = k4 * 4 + j;
#pragma unroll
      for (int f = 0; f < 32; ++f) h[f] += xs * W1[k * 32 + f];
    }
  }
  float o0 = b2[0], o1 = b2[1];
#pragma unroll
  for (int f = 0; f < 32; ++f) {
    float hv = fmaxf(h[f], 0.f);
    o0 += hv * W2[f * 2 + 0];
    o1 += hv * W2[f * 2 + 1];
  }
  float2 o;
  o.x = o0; o.y = o1;
  *(float2*)(out + (size_t)node * 2) = o;   // lane-consecutive: already coalesced
}

extern "C" void kernel_launch(void* const* d_in, const int* in_sizes, int n_in,
                              void* d_out, int out_size, void* d_ws, size_t ws_size,
                              hipStream_t stream) {
  const float* x_ind = (const float*)d_in[0];
  const float* x_com = (const float*)d_in[1];
  const float* x_tru = (const float*)d_in[2];
  const int*   ei    = (const int*)d_in[3];
  const float* W_ind = (const float*)d_in[4];
  const float* b_ind = (const float*)d_in[5];
  const float* W_com = (const float*)d_in[6];
  const float* b_com = (const float*)d_in[7];
  const float* W_tru = (const float*)d_in[8];
  const float* b_tru = (const float*)d_in[9];
  const float* W1l = (const float*)d_in[10];
  const float* W1r = (const float*)d_in[11];
  const float* b1  = (const float*)d_in[12];
  const float* W2l = (const float*)d_in[13];
  const float* W2r = (const float*)d_in[14];
  const float* b2  = (const float*)d_in[15];
  const float* Wc1 = (const float*)d_in[16];
  const float* bc1 = (const float*)d_in[17];
  const float* Wc2 = (const float*)d_in[18];
  const float* bc2 = (const float*)d_in[19];

  const int* srcp = ei;           // edge_index[0]
  const int* dstp = ei + NEDGE;   // edge_index[1]

  // workspace layout (~212 MB; round-1 proved >=252 MB available)
  size_t fcount = (size_t)NTOT * HDIM;  // 19.2M elems per feature tensor
  float* xf = (float*)d_ws;                        // fp32 final features (76.8 MB)
  unsigned* packed = (unsigned*)xf;                // ALIAS: dead before xf written
  unsigned short* xb0 = (unsigned short*)(xf + fcount);   // bf16 layer-0 features
  unsigned short* xb1 = xb0 + fcount;                     // bf16 layer-1 features
  unsigned short* mnb = xb1 + fcount;                     // bf16 mean (stream)
  int* eidx    = (int*)(mnb + fcount);
  int* nodeoff = eidx + NEDGE;
  int* deg     = nodeoff + NTOT;
  int* chist   = deg + NTOT;
  int* cbase   = chist + NCB;
  int* ccur    = cbase + NCB;
  size_t needed = (size_t)((char*)(ccur + NCB) - (char*)d_ws) + 64;
  if (ws_size < needed) return;  // would corrupt; fail visibly instead

  (void)hipMemsetAsync(chist, 0, (size_t)NCB * sizeof(int), stream);

  // encoders (write bf16 xb0; independent of edge pipeline)
  encode_kernel<32><<<(N_IND + 255) / 256, 256, 0, stream>>>(x_ind, W_ind, b_ind, xb0, N_IND, 0);
  encode_kernel<48><<<(N_COM + 255) / 256, 256, 0, stream>>>(x_com, W_com, b_com, xb0, N_COM, N_IND);
  encode_kernel<24><<<(N_TRU + 255) / 256, 256, 0, stream>>>(x_tru, W_tru, b_tru, xb0, N_TRU, N_IND + N_COM);

  // coarse partition -> per-coarse-bucket counting sort -> node-grouped CSR
  coarse_hist_kernel<<<NCHUNKS, 256, 0, stream>>>(dstp, chist, NEDGE);
  coarse_scan_kernel<<<1, 512, 0, stream>>>(chist, cbase, ccur);
  coarse_scatter_kernel<<<NCHUNKS, 256, 0, stream>>>(srcp, dstp, ccur, packed, NEDGE);
  sort_coarse_kernel<<<NCB, 256, 0, stream>>>(packed, cbase, chist, eidx, nodeoff, deg);

  // SAGE layer 1: aggregate bf16 -> bf16 mean; combine -> bf16 x1
  aggregate_kernel<<<(NTOT * 16 + 255) / 256, 256, 0, stream>>>(xb0, nodeoff, deg, eidx, mnb, NTOT);
  combine_kernel<<<(NTOT + 127) / 128, 256, 0, stream>>>(mnb, xb0, W1l, W1r, b1, nullptr, xb1, NTOT);

  // SAGE layer 2: aggregate bf16 -> bf16 mean; combine -> fp32 xf
  aggregate_kernel<<<(NTOT * 16 + 255) / 256, 256, 0, stream>>>(xb1, nodeoff, deg, eidx, mnb, NTOT);
  combine_kernel<<<(NTOT + 127) / 128, 256, 0, stream>>>(mnb, xb1, W2l, W2r, b2, xf, nullptr, NTOT);

  // classifier (fp32 input, unquantized)
  classifier_kernel<<<(NTOT + 255) / 256, 256, 0, stream>>>(xf, Wc1, bc1, Wc2, bc2,
                                                            (float*)d_out, NTOT);
}

// Round 12
// 815.510 us; speedup vs baseline: 1.6464x; 1.6464x over previous
//
#include <hip/hip_runtime.h>

#define N_IND 100000
#define N_COM 100000
#define N_TRU 100000
#define NTOT  300000
#define NEDGE 4800000
#define HDIM  64
#define CHUNK 8192
#define NCHUNKS 586   // ceil(NEDGE/CHUNK)
#define NCB 293       // ceil(NTOT/1024) coarse buckets of 1024 nodes
#define PADW 33       // 32 cols + 1 pad (encoder epilogue)

typedef float v4f __attribute__((ext_vector_type(4)));
typedef unsigned short v4u __attribute__((ext_vector_type(4)));  // clang vector: ok for nontemporal builtins

static __device__ __forceinline__ float elem4(const float4 v, int j) {
  return j == 0 ? v.x : j == 1 ? v.y : j == 2 ? v.z : v.w;
}

// fp32 -> bf16 round-to-nearest-even
static __device__ __forceinline__ unsigned short f2bf(float f) {
  unsigned u = __float_as_uint(f);
  unsigned r = (u + 0x7FFFu + ((u >> 16) & 1u)) >> 16;
  return (unsigned short)r;
}
static __device__ __forceinline__ float bf2f(unsigned short h) {
  return __uint_as_float(((unsigned)h) << 16);
}

// Coalesced bf16 epilogue for encoder (256 rows, 2 stages of 32 cols).
static __device__ __forceinline__ void store_rows_bf16(
    unsigned short* __restrict__ out, float* __restrict__ st, const float* acc,
    int node0, int rows, int tid, bool active) {
#pragma unroll
  for (int stage = 0; stage < 2; ++stage) {
    __syncthreads();
    if (active) {
#pragma unroll
      for (int j = 0; j < 32; ++j) st[tid * PADW + j] = acc[stage * 32 + j];
    }
    __syncthreads();
#pragma unroll
    for (int it = 0; it < 8; ++it) {
      int e = it * 256 + tid;
      int r = e >> 3;
      int c = (e & 7) * 4;
      if (r < rows) {
        v4u o;
        o.x = f2bf(st[r * PADW + c + 0]);
        o.y = f2bf(st[r * PADW + c + 1]);
        o.z = f2bf(st[r * PADW + c + 2]);
        o.w = f2bf(st[r * PADW + c + 3]);
        *(v4u*)(out + (size_t)(node0 + r) * HDIM + stage * 32 + c) = o;
      }
    }
  }
}

// ---------------- encoder: xb[base+n] = bf16(x[n] @ W + b) ----------------
template <int K>
__global__ __launch_bounds__(256, 2) void encode_kernel(
    const float* __restrict__ xin, const float* __restrict__ W,
    const float* __restrict__ b, unsigned short* __restrict__ xbout, int n, int base) {
  __shared__ float st[256 * PADW];
  int tid = threadIdx.x;
  int node0 = blockIdx.x * 256;
  int node = node0 + tid;
  bool active = node < n;
  int rows = min(256, n - node0);
  float acc[HDIM];
  if (active) {
    float4 row[K / 4];
    const float4* xv = (const float4*)(xin + (size_t)node * K);
#pragma unroll
    for (int i = 0; i < K / 4; ++i) row[i] = xv[i];
#pragma unroll
    for (int f = 0; f < HDIM; ++f) acc[f] = b[f];  // uniform -> s_load
#pragma unroll
    for (int k4 = 0; k4 < K / 4; ++k4) {
#pragma unroll
      for (int j = 0; j < 4; ++j) {
        float xs = elem4(row[k4], j);
        int k = k4 * 4 + j;
#pragma unroll
        for (int f = 0; f < HDIM; ++f) acc[f] += xs * W[k * HDIM + f];
      }
    }
  }
  store_rows_bf16(xbout + (size_t)base * HDIM, st, acc, node0, rows, tid, active);
}

// ---------------- coarse histogram: LDS-aggregated, 293 bins ----------------
__global__ __launch_bounds__(256) void coarse_hist_kernel(const int* __restrict__ dst,
                                                          int* __restrict__ chist, int e) {
  __shared__ int h[NCB];
  int tid = threadIdx.x;
  int start = blockIdx.x * CHUNK;
  int len = min(CHUNK, e - start);
  for (int i = tid; i < NCB; i += 256) h[i] = 0;
  __syncthreads();
  for (int i = tid; i < len; i += 256) atomicAdd(&h[dst[start + i] >> 10], 1);
  __syncthreads();
  for (int b = tid; b < NCB; b += 256) {
    int c = h[b];
    if (c > 0) atomicAdd(&chist[b], c);
  }
}

// ---------------- exclusive scan of 293 coarse counts ----------------
__global__ __launch_bounds__(512) void coarse_scan_kernel(const int* __restrict__ chist,
                                                          int* __restrict__ cbase,
                                                          int* __restrict__ ccur) {
  __shared__ int sv[512];
  int t = threadIdx.x;
  sv[t] = (t < NCB) ? chist[t] : 0;
  __syncthreads();
  for (int o = 1; o < 512; o <<= 1) {
    int y = (t >= o) ? sv[t - o] : 0;
    __syncthreads();
    sv[t] += y;
    __syncthreads();
  }
  if (t < NCB) {
    int ex = (t == 0) ? 0 : sv[t - 1];
    cbase[t] = ex;
    ccur[t] = ex;
  }
}

// ---------------- coarse scatter: block-aggregated reservation, dense runs ----------------
// packed word = (src << 10) | (dst & 1023); src < 2^19 -> 29 bits.
__global__ __launch_bounds__(256) void coarse_scatter_kernel(
    const int* __restrict__ src, const int* __restrict__ dst,
    int* __restrict__ ccur, unsigned* __restrict__ packed, int e) {
  __shared__ int h[NCB];
  __shared__ int lbase[NCB];
  int tid = threadIdx.x;
  int start = blockIdx.x * CHUNK;
  int len = min(CHUNK, e - start);
  for (int i = tid; i < NCB; i += 256) h[i] = 0;
  __syncthreads();
  for (int i = tid; i < len; i += 256) atomicAdd(&h[dst[start + i] >> 10], 1);
  __syncthreads();
  for (int b = tid; b < NCB; b += 256) {
    int c = h[b];
    lbase[b] = (c > 0) ? atomicAdd(&ccur[b], c) : 0;  // reserve contiguous run
  }
  __syncthreads();
  for (int i = tid; i < NCB; i += 256) h[i] = 0;  // reuse as rank counters
  __syncthreads();
  for (int i = tid; i < len; i += 256) {
    int d = dst[start + i];
    int s = src[start + i];
    int b = d >> 10;
    int r = atomicAdd(&h[b], 1);
    packed[lbase[b] + r] = ((unsigned)s << 10) | (unsigned)(d & 1023);
  }
}

// ---------------- per-coarse-bucket counting sort -> node-grouped CSR ----------------
__global__ __launch_bounds__(256) void sort_coarse_kernel(
    const unsigned* __restrict__ packed, const int* __restrict__ cbase,
    const int* __restrict__ chist, int* __restrict__ eidx,
    int* __restrict__ nodeoff, int* __restrict__ deg) {
  __shared__ int cnts[1024];
  __shared__ int cur[1024];
  __shared__ int part[256];
  int cb = blockIdx.x;
  int tid = threadIdx.x;
  for (int i = tid; i < 1024; i += 256) cnts[i] = 0;
  __syncthreads();
  int base = cbase[cb];
  int cnt = chist[cb];
  for (int i = tid; i < cnt; i += 256)
    atomicAdd(&cnts[packed[base + i] & 1023u], 1);
  __syncthreads();
  int c0 = cnts[4 * tid + 0], c1 = cnts[4 * tid + 1];
  int c2 = cnts[4 * tid + 2], c3 = cnts[4 * tid + 3];
  part[tid] = c0 + c1 + c2 + c3;
  __syncthreads();
  for (int o = 1; o < 256; o <<= 1) {
    int y = (tid >= o) ? part[tid - o] : 0;
    __syncthreads();
    part[tid] += y;
    __syncthreads();
  }
  int pre = (tid == 0) ? 0 : part[tid - 1];
  int e0 = pre, e1 = e0 + c0, e2 = e1 + c1, e3 = e2 + c2;
  cur[4 * tid + 0] = e0; cur[4 * tid + 1] = e1;
  cur[4 * tid + 2] = e2; cur[4 * tid + 3] = e3;
  int nodebase = (cb << 10) + 4 * tid;
  if (nodebase + 0 < NTOT) { deg[nodebase + 0] = c0; nodeoff[nodebase + 0] = base + e0; }
  if (nodebase + 1 < NTOT) { deg[nodebase + 1] = c1; nodeoff[nodebase + 1] = base + e1; }
  if (nodebase + 2 < NTOT) { deg[nodebase + 2] = c2; nodeoff[nodebase + 2] = base + e2; }
  if (nodebase + 3 < NTOT) { deg[nodebase + 3] = c3; nodeoff[nodebase + 3] = base + e3; }
  __syncthreads();
  for (int i = tid; i < cnt; i += 256) {
    unsigned pr = packed[base + i];
    int dl = (int)(pr & 1023u);
    int r = atomicAdd(&cur[dl], 1);
    eidx[base + r] = (int)(pr >> 10);  // 64 KB region exclusive to this block
  }
}

// ---------------- mean aggregation: bf16 in, bf16 out, 16 lanes/node ----------------
__global__ __launch_bounds__(256) void aggregate_kernel(
    const unsigned short* __restrict__ xb, const int* __restrict__ off,
    const int* __restrict__ deg, const int* __restrict__ eidx,
    unsigned short* __restrict__ meanb, int n) {
  int tid = blockIdx.x * 256 + threadIdx.x;
  int node = tid >> 4;
  int lane = tid & 15;
  if (node >= n) return;
  int start = off[node];
  int d = deg[node];
  const v4u* xv = (const v4u*)xb;   // row = 16 x v4u (128 B)
  float4 a0 = make_float4(0.f, 0.f, 0.f, 0.f);
  float4 a1 = make_float4(0.f, 0.f, 0.f, 0.f);
  float4 a2 = make_float4(0.f, 0.f, 0.f, 0.f);
  float4 a3 = make_float4(0.f, 0.f, 0.f, 0.f);
  int i = 0;
  for (; i + 4 <= d; i += 4) {
    int s0 = eidx[start + i + 0];
    int s1 = eidx[start + i + 1];
    int s2 = eidx[start + i + 2];
    int s3 = eidx[start + i + 3];
    v4u v0 = xv[(size_t)s0 * 16 + lane];
    v4u v1 = xv[(size_t)s1 * 16 + lane];
    v4u v2 = xv[(size_t)s2 * 16 + lane];
    v4u v3 = xv[(size_t)s3 * 16 + lane];
    a0.x += bf2f(v0.x); a0.y += bf2f(v0.y); a0.z += bf2f(v0.z); a0.w += bf2f(v0.w);
    a1.x += bf2f(v1.x); a1.y += bf2f(v1.y); a1.z += bf2f(v1.z); a1.w += bf2f(v1.w);
    a2.x += bf2f(v2.x); a2.y += bf2f(v2.y); a2.z += bf2f(v2.z); a2.w += bf2f(v2.w);
    a3.x += bf2f(v3.x); a3.y += bf2f(v3.y); a3.z += bf2f(v3.z); a3.w += bf2f(v3.w);
  }
  for (; i < d; ++i) {
    int s = eidx[start + i];
    v4u v = xv[(size_t)s * 16 + lane];
    a0.x += bf2f(v.x); a0.y += bf2f(v.y); a0.z += bf2f(v.z); a0.w += bf2f(v.w);
  }
  float inv = 1.0f / (float)(d > 0 ? d : 1);
  v4u o;
  o.x = f2bf((a0.x + a1.x + a2.x + a3.x) * inv);
  o.y = f2bf((a0.y + a1.y + a2.y + a3.y) * inv);
  o.z = f2bf((a0.z + a1.z + a2.z + a3.z) * inv);
  o.w = f2bf((a0.w + a1.w + a2.w + a3.w) * inv);
  // mean is a pure stream (read once by combine): keep it out of L3
  __builtin_nontemporal_store(o, (v4u*)meanb + (size_t)node * 16 + lane);
}

// ---------------- combine: relu(mean@Wl + x@Wr + b); 2 threads/node ----------------
// Output split across wave pairs: waves 0-1 compute cols 0..31, waves 2-3 cols 32..63
// for the same 128 nodes. half is forced into an SGPR via readfirstlane (it is
// wave-uniform by construction) so the weight pointers stay SCALAR -> s_load.
// R11 lesson: without readfirstlane the compiler treats tid>>7 as divergent and
// every weight access becomes a per-lane VMEM load (336 us vs 141 us).
__global__ __launch_bounds__(256, 4) void combine_kernel(
    const unsigned short* __restrict__ meanb, const unsigned short* __restrict__ xb,
    const float* __restrict__ Wl, const float* __restrict__ Wr,
    const float* __restrict__ bb, float* __restrict__ outf,
    unsigned short* __restrict__ outb, int n) {
  __shared__ float st[128 * 65];
  int tid = threadIdx.x;
  int half = __builtin_amdgcn_readfirstlane(tid >> 7);  // wave-uniform -> SGPR
  int nl = tid & 127;
  int node0 = blockIdx.x * 128;
  int node = node0 + nl;
  bool active = node < n;
  int rows = min(128, n - node0);
  float acc[32];
  if (active) {
    const float* Wlh = Wl + half * 32;   // scalar pointer -> s_load weights
    const float* Wrh = Wr + half * 32;
#pragma unroll
    for (int f = 0; f < 32; ++f) acc[f] = bb[half * 32 + f];
    // phase 1: mean(bf16) @ Wl — process row in 4-chunk bursts (line-dense loads)
    const v4u* mv = (const v4u*)(meanb + (size_t)node * HDIM);
#pragma unroll
    for (int c = 0; c < 4; ++c) {
      v4u hh[4];
#pragma unroll
      for (int q = 0; q < 4; ++q) hh[q] = __builtin_nontemporal_load(mv + c * 4 + q);
#pragma unroll
      for (int q = 0; q < 4; ++q) {
        float m0 = bf2f(hh[q].x), m1 = bf2f(hh[q].y), m2 = bf2f(hh[q].z), m3 = bf2f(hh[q].w);
        int k = c * 16 + q * 4;
#pragma unroll
        for (int f = 0; f < 32; ++f)
          acc[f] += m0 * Wlh[(k + 0) * HDIM + f] + m1 * Wlh[(k + 1) * HDIM + f]
                  + m2 * Wlh[(k + 2) * HDIM + f] + m3 * Wlh[(k + 3) * HDIM + f];
      }
    }
    // phase 2: x(bf16) @ Wr
    const v4u* xv = (const v4u*)(xb + (size_t)node * HDIM);
#pragma unroll
    for (int c = 0; c < 4; ++c) {
      v4u hh[4];
#pragma unroll
      for (int q = 0; q < 4; ++q) hh[q] = xv[c * 4 + q];
#pragma unroll
      for (int q = 0; q < 4; ++q) {
        float m0 = bf2f(hh[q].x), m1 = bf2f(hh[q].y), m2 = bf2f(hh[q].z), m3 = bf2f(hh[q].w);
        int k = c * 16 + q * 4;
#pragma unroll
        for (int f = 0; f < 32; ++f)
          acc[f] += m0 * Wrh[(k + 0) * HDIM + f] + m1 * Wrh[(k + 1) * HDIM + f]
                  + m2 * Wrh[(k + 2) * HDIM + f] + m3 * Wrh[(k + 3) * HDIM + f];
      }
    }
#pragma unroll
    for (int f = 0; f < 32; ++f) acc[f] = fmaxf(acc[f], 0.f);
    // stage to LDS (pad 65: <=2-way bank alias, free)
#pragma unroll
    for (int j = 0; j < 32; ++j) st[nl * 65 + half * 32 + j] = acc[j];
  }
  __syncthreads();
  // coalesced copy-out: 128 rows x 64 cols, line-complete stores
#pragma unroll
  for (int it = 0; it < 8; ++it) {
    int e = it * 256 + tid;     // float4 index; 16 per row
    int r = e >> 4;
    int c = (e & 15) * 4;
    if (r < rows) {
      const float* ap = &st[r * 65 + c];
      if (outb) {
        v4u o;
        o.x = f2bf(ap[0]); o.y = f2bf(ap[1]); o.z = f2bf(ap[2]); o.w = f2bf(ap[3]);
        *(v4u*)(outb + (size_t)(node0 + r) * HDIM + c) = o;
      } else {
        float4 o;
        o.x = ap[0]; o.y = ap[1]; o.z = ap[2]; o.w = ap[3];
        *(float4*)(outf + (size_t)(node0 + r) * HDIM + c) = o;
      }
    }
  }
}

// ---------------- classifier: out = relu(x@Wc1+bc1)@Wc2 + bc2  (fp32 input) ----------------
__global__ __launch_bounds__(256, 2) void classifier_kernel(
    const float* __restrict__ x, const float* __restrict__ W1, const float* __restrict__ b1,
    const float* __restrict__ W2, const float* __restrict__ b2,
    float* __restrict__ out, int n) {
  int node = blockIdx.x * 256 + threadIdx.x;
  if (node >= n) return;
  float4 row[16];
  const float4* xv = (const float4*)(x + (size_t)node * HDIM);
#pragma unroll
  for (int i = 0; i < 16; ++i) row[i] = xv[i];
  float h[32];
#pragma unroll
  for (int f = 0; f < 32; ++f) h[f] = b1[f];
#pragma unroll
  for (int k4 = 0; k4 < 16; ++k4) {
#pragma unroll
    for (int j = 0; j < 4; ++j) {
      float xs = elem4(row[k4], j);
      int k = k4 * 4 + j;
#pragma unroll
      for (int f = 0; f < 32; ++f) h[f] += xs * W1[k * 32 + f];
    }
  }
  float o0 = b2[0], o1 = b2[1];
#pragma unroll
  for (int f = 0; f < 32; ++f) {
    float hv = fmaxf(h[f], 0.f);
    o0 += hv * W2[f * 2 + 0];
    o1 += hv * W2[f * 2 + 1];
  }
  float2 o;
  o.x = o0; o.y = o1;
  *(float2*)(out + (size_t)node * 2) = o;   // lane-consecutive: already coalesced
}

extern "C" void kernel_launch(void* const* d_in, const int* in_sizes, int n_in,
                              void* d_out, int out_size, void* d_ws, size_t ws_size,
                              hipStream_t stream) {
  const float* x_ind = (const float*)d_in[0];
  const float* x_com = (const float*)d_in[1];
  const float* x_tru = (const float*)d_in[2];
  const int*   ei    = (const int*)d_in[3];
  const float* W_ind = (const float*)d_in[4];
  const float* b_ind = (const float*)d_in[5];
  const float* W_com = (const float*)d_in[6];
  const float* b_com = (const float*)d_in[7];
  const float* W_tru = (const float*)d_in[8];
  const float* b_tru = (const float*)d_in[9];
  const float* W1l = (const float*)d_in[10];
  const float* W1r = (const float*)d_in[11];
  const float* b1  = (const float*)d_in[12];
  const float* W2l = (const float*)d_in[13];
  const float* W2r = (const float*)d_in[14];
  const float* b2  = (const float*)d_in[15];
  const float* Wc1 = (const float*)d_in[16];
  const float* bc1 = (const float*)d_in[17];
  const float* Wc2 = (const float*)d_in[18];
  const float* bc2 = (const float*)d_in[19];

  const int* srcp = ei;           // edge_index[0]
  const int* dstp = ei + NEDGE;   // edge_index[1]

  // workspace layout (~212 MB; round-1 proved >=252 MB available)
  size_t fcount = (size_t)NTOT * HDIM;  // 19.2M elems per feature tensor
  float* xf = (float*)d_ws;                        // fp32 final features (76.8 MB)
  unsigned* packed = (unsigned*)xf;                // ALIAS: dead before xf written
  unsigned short* xb0 = (unsigned short*)(xf + fcount);   // bf16 layer-0 features
  unsigned short* xb1 = xb0 + fcount;                     // bf16 layer-1 features
  unsigned short* mnb = xb1 + fcount;                     // bf16 mean (stream)
  int* eidx    = (int*)(mnb + fcount);
  int* nodeoff = eidx + NEDGE;
  int* deg     = nodeoff + NTOT;
  int* chist   = deg + NTOT;
  int* cbase   = chist + NCB;
  int* ccur    = cbase + NCB;
  size_t needed = (size_t)((char*)(ccur + NCB) - (char*)d_ws) + 64;
  if (ws_size < needed) return;  // would corrupt; fail visibly instead

  (void)hipMemsetAsync(chist, 0, (size_t)NCB * sizeof(int), stream);

  // encoders (write bf16 xb0; independent of edge pipeline)
  encode_kernel<32><<<(N_IND + 255) / 256, 256, 0, stream>>>(x_ind, W_ind, b_ind, xb0, N_IND, 0);
  encode_kernel<48><<<(N_COM + 255) / 256, 256, 0, stream>>>(x_com, W_com, b_com, xb0, N_COM, N_IND);
  encode_kernel<24><<<(N_TRU + 255) / 256, 256, 0, stream>>>(x_tru, W_tru, b_tru, xb0, N_TRU, N_IND + N_COM);

  // coarse partition -> per-coarse-bucket counting sort -> node-grouped CSR
  coarse_hist_kernel<<<NCHUNKS, 256, 0, stream>>>(dstp, chist, NEDGE);
  coarse_scan_kernel<<<1, 512, 0, stream>>>(chist, cbase, ccur);
  coarse_scatter_kernel<<<NCHUNKS, 256, 0, stream>>>(srcp, dstp, ccur, packed, NEDGE);
  sort_coarse_kernel<<<NCB, 256, 0, stream>>>(packed, cbase, chist, eidx, nodeoff, deg);

  // SAGE layer 1: aggregate bf16 -> bf16 mean; combine -> bf16 x1
  aggregate_kernel<<<(NTOT * 16 + 255) / 256, 256, 0, stream>>>(xb0, nodeoff, deg, eidx, mnb, NTOT);
  combine_kernel<<<(NTOT + 127) / 128, 256, 0, stream>>>(mnb, xb0, W1l, W1r, b1, nullptr, xb1, NTOT);

  // SAGE layer 2: aggregate bf16 -> bf16 mean; combine -> fp32 xf
  aggregate_kernel<<<(NTOT * 16 + 255) / 256, 256, 0, stream>>>(xb1, nodeoff, deg, eidx, mnb, NTOT);
  combine_kernel<<<(NTOT + 127) / 128, 256, 0, stream>>>(mnb, xb1, W2l, W2r, b2, xf, nullptr, NTOT);

  // classifier (fp32 input, unquantized)
  classifier_kernel<<<(NTOT + 255) / 256, 256, 0, stream>>>(xf, Wc1, bc1, Wc2, bc2,
                                                            (float*)d_out, NTOT);
}

// Round 13
// 701.600 us; speedup vs baseline: 1.9137x; 1.1624x over previous
//
#include <hip/hip_runtime.h>

#define N_IND 100000
#define N_COM 100000
#define N_TRU 100000
#define NTOT  300000
#define NEDGE 4800000
#define HDIM  64
#define CHUNK 8192
#define NCHUNKS 586   // ceil(NEDGE/CHUNK)
#define NCB 293       // ceil(NTOT/1024) coarse buckets of 1024 nodes
#define PADW 33       // 32 cols + 1 pad (encoder epilogue)
#define NTILES 18750  // NTOT / 16 exactly
#define CMB_BLOCKS 1184

typedef float v4f __attribute__((ext_vector_type(4)));
typedef unsigned short v4u __attribute__((ext_vector_type(4)));
typedef _Float16 v8h __attribute__((ext_vector_type(8)));

static __device__ __forceinline__ float elem4(const float4 v, int j) {
  return j == 0 ? v.x : j == 1 ? v.y : j == 2 ? v.z : v.w;
}

// fp32 <-> fp16 (RTN via v_cvt)
static __device__ __forceinline__ unsigned short f2h(float f) {
  _Float16 h = (_Float16)f;
  return __builtin_bit_cast(unsigned short, h);
}
static __device__ __forceinline__ float h2f(unsigned short u) {
  return (float)__builtin_bit_cast(_Float16, u);
}

// Coalesced fp16 epilogue for encoder (256 rows, 2 stages of 32 cols).
static __device__ __forceinline__ void store_rows_f16(
    unsigned short* __restrict__ out, float* __restrict__ st, const float* acc,
    int node0, int rows, int tid, bool active) {
#pragma unroll
  for (int stage = 0; stage < 2; ++stage) {
    __syncthreads();
    if (active) {
#pragma unroll
      for (int j = 0; j < 32; ++j) st[tid * PADW + j] = acc[stage * 32 + j];
    }
    __syncthreads();
#pragma unroll
    for (int it = 0; it < 8; ++it) {
      int e = it * 256 + tid;
      int r = e >> 3;
      int c = (e & 7) * 4;
      if (r < rows) {
        v4u o;
        o.x = f2h(st[r * PADW + c + 0]);
        o.y = f2h(st[r * PADW + c + 1]);
        o.z = f2h(st[r * PADW + c + 2]);
        o.w = f2h(st[r * PADW + c + 3]);
        *(v4u*)(out + (size_t)(node0 + r) * HDIM + stage * 32 + c) = o;
      }
    }
  }
}

// ---------------- encoder: xh[base+n] = fp16(x[n] @ W + b) ----------------
template <int K>
__global__ __launch_bounds__(256, 2) void encode_kernel(
    const float* __restrict__ xin, const float* __restrict__ W,
    const float* __restrict__ b, unsigned short* __restrict__ xhout, int n, int base) {
  __shared__ float st[256 * PADW];
  int tid = threadIdx.x;
  int node0 = blockIdx.x * 256;
  int node = node0 + tid;
  bool active = node < n;
  int rows = min(256, n - node0);
  float acc[HDIM];
  if (active) {
    float4 row[K / 4];
    const float4* xv = (const float4*)(xin + (size_t)node * K);
#pragma unroll
    for (int i = 0; i < K / 4; ++i) row[i] = xv[i];
#pragma unroll
    for (int f = 0; f < HDIM; ++f) acc[f] = b[f];  // uniform -> s_load
#pragma unroll
    for (int k4 = 0; k4 < K / 4; ++k4) {
#pragma unroll
      for (int j = 0; j < 4; ++j) {
        float xs = elem4(row[k4], j);
        int k = k4 * 4 + j;
#pragma unroll
        for (int f = 0; f < HDIM; ++f) acc[f] += xs * W[k * HDIM + f];
      }
    }
  }
  store_rows_f16(xhout + (size_t)base * HDIM, st, acc, node0, rows, tid, active);
}

// ---------------- weight prep: fp32 -> fp16, swizzled to B-fragment order ----------------
// frag layout per 64x64 matrix: out[ts*512 + l*8 + j] = W[s*32 + (l>>4)*8 + j][t*16 + (l&15)]
// where ts = t*2+s. A v8h load at index (ts*64 + lane) yields lane's B fragment.
__global__ __launch_bounds__(256) void prep_weights_kernel(
    const float* __restrict__ W1l, const float* __restrict__ W1r,
    const float* __restrict__ W2l, const float* __restrict__ W2r,
    unsigned short* __restrict__ out) {
  const float* Ws[4] = {W1l, W1r, W2l, W2r};
  int tid = threadIdx.x;
  for (int m = 0; m < 4; ++m) {
    const float* W = Ws[m];
    unsigned short* o = out + m * 4096;
    for (int idx = tid; idx < 4096; idx += 256) {
      int j = idx & 7;
      int l = (idx >> 3) & 63;
      int ts = idx >> 9;
      int t = ts >> 1, s = ts & 1;
      int k = s * 32 + (l >> 4) * 8 + j;
      int n = t * 16 + (l & 15);
      o[idx] = f2h(W[k * HDIM + n]);
    }
  }
}

// ---------------- coarse histogram: LDS-aggregated, 293 bins ----------------
__global__ __launch_bounds__(256) void coarse_hist_kernel(const int* __restrict__ dst,
                                                          int* __restrict__ chist, int e) {
  __shared__ int h[NCB];
  int tid = threadIdx.x;
  int start = blockIdx.x * CHUNK;
  int len = min(CHUNK, e - start);
  for (int i = tid; i < NCB; i += 256) h[i] = 0;
  __syncthreads();
  for (int i = tid; i < len; i += 256) atomicAdd(&h[dst[start + i] >> 10], 1);
  __syncthreads();
  for (int b = tid; b < NCB; b += 256) {
    int c = h[b];
    if (c > 0) atomicAdd(&chist[b], c);
  }
}

// ---------------- exclusive scan of 293 coarse counts ----------------
__global__ __launch_bounds__(512) void coarse_scan_kernel(const int* __restrict__ chist,
                                                          int* __restrict__ cbase,
                                                          int* __restrict__ ccur) {
  __shared__ int sv[512];
  int t = threadIdx.x;
  sv[t] = (t < NCB) ? chist[t] : 0;
  __syncthreads();
  for (int o = 1; o < 512; o <<= 1) {
    int y = (t >= o) ? sv[t - o] : 0;
    __syncthreads();
    sv[t] += y;
    __syncthreads();
  }
  if (t < NCB) {
    int ex = (t == 0) ? 0 : sv[t - 1];
    cbase[t] = ex;
    ccur[t] = ex;
  }
}

// ---------------- coarse scatter: block-aggregated reservation, dense runs ----------------
__global__ __launch_bounds__(256) void coarse_scatter_kernel(
    const int* __restrict__ src, const int* __restrict__ dst,
    int* __restrict__ ccur, unsigned* __restrict__ packed, int e) {
  __shared__ int h[NCB];
  __shared__ int lbase[NCB];
  int tid = threadIdx.x;
  int start = blockIdx.x * CHUNK;
  int len = min(CHUNK, e - start);
  for (int i = tid; i < NCB; i += 256) h[i] = 0;
  __syncthreads();
  for (int i = tid; i < len; i += 256) atomicAdd(&h[dst[start + i] >> 10], 1);
  __syncthreads();
  for (int b = tid; b < NCB; b += 256) {
    int c = h[b];
    lbase[b] = (c > 0) ? atomicAdd(&ccur[b], c) : 0;  // reserve contiguous run
  }
  __syncthreads();
  for (int i = tid; i < NCB; i += 256) h[i] = 0;  // reuse as rank counters
  __syncthreads();
  for (int i = tid; i < len; i += 256) {
    int d = dst[start + i];
    int s = src[start + i];
    int b = d >> 10;
    int r = atomicAdd(&h[b], 1);
    packed[lbase[b] + r] = ((unsigned)s << 10) | (unsigned)(d & 1023);
  }
}

// ---------------- per-coarse-bucket counting sort -> node-grouped CSR ----------------
__global__ __launch_bounds__(256) void sort_coarse_kernel(
    const unsigned* __restrict__ packed, const int* __restrict__ cbase,
    const int* __restrict__ chist, int* __restrict__ eidx,
    int* __restrict__ nodeoff, int* __restrict__ deg) {
  __shared__ int cnts[1024];
  __shared__ int cur[1024];
  __shared__ int part[256];
  int cb = blockIdx.x;
  int tid = threadIdx.x;
  for (int i = tid; i < 1024; i += 256) cnts[i] = 0;
  __syncthreads();
  int base = cbase[cb];
  int cnt = chist[cb];
  for (int i = tid; i < cnt; i += 256)
    atomicAdd(&cnts[packed[base + i] & 1023u], 1);
  __syncthreads();
  int c0 = cnts[4 * tid + 0], c1 = cnts[4 * tid + 1];
  int c2 = cnts[4 * tid + 2], c3 = cnts[4 * tid + 3];
  part[tid] = c0 + c1 + c2 + c3;
  __syncthreads();
  for (int o = 1; o < 256; o <<= 1) {
    int y = (tid >= o) ? part[tid - o] : 0;
    __syncthreads();
    part[tid] += y;
    __syncthreads();
  }
  int pre = (tid == 0) ? 0 : part[tid - 1];
  int e0 = pre, e1 = e0 + c0, e2 = e1 + c1, e3 = e2 + c2;
  cur[4 * tid + 0] = e0; cur[4 * tid + 1] = e1;
  cur[4 * tid + 2] = e2; cur[4 * tid + 3] = e3;
  int nodebase = (cb << 10) + 4 * tid;
  if (nodebase + 0 < NTOT) { deg[nodebase + 0] = c0; nodeoff[nodebase + 0] = base + e0; }
  if (nodebase + 1 < NTOT) { deg[nodebase + 1] = c1; nodeoff[nodebase + 1] = base + e1; }
  if (nodebase + 2 < NTOT) { deg[nodebase + 2] = c2; nodeoff[nodebase + 2] = base + e2; }
  if (nodebase + 3 < NTOT) { deg[nodebase + 3] = c3; nodeoff[nodebase + 3] = base + e3; }
  __syncthreads();
  for (int i = tid; i < cnt; i += 256) {
    unsigned pr = packed[base + i];
    int dl = (int)(pr & 1023u);
    int r = atomicAdd(&cur[dl], 1);
    eidx[base + r] = (int)(pr >> 10);  // 64 KB region exclusive to this block
  }
}

// ---------------- mean aggregation: fp16 in, fp16 out, 16 lanes/node ----------------
__global__ __launch_bounds__(256) void aggregate_kernel(
    const unsigned short* __restrict__ xh, const int* __restrict__ off,
    const int* __restrict__ deg, const int* __restrict__ eidx,
    unsigned short* __restrict__ meanh, int n) {
  int tid = blockIdx.x * 256 + threadIdx.x;
  int node = tid >> 4;
  int lane = tid & 15;
  if (node >= n) return;
  int start = off[node];
  int d = deg[node];
  const v4u* xv = (const v4u*)xh;   // row = 16 x v4u (128 B)
  float4 a0 = make_float4(0.f, 0.f, 0.f, 0.f);
  float4 a1 = make_float4(0.f, 0.f, 0.f, 0.f);
  float4 a2 = make_float4(0.f, 0.f, 0.f, 0.f);
  float4 a3 = make_float4(0.f, 0.f, 0.f, 0.f);
  int i = 0;
  for (; i + 4 <= d; i += 4) {
    int s0 = eidx[start + i + 0];
    int s1 = eidx[start + i + 1];
    int s2 = eidx[start + i + 2];
    int s3 = eidx[start + i + 3];
    v4u v0 = xv[(size_t)s0 * 16 + lane];
    v4u v1 = xv[(size_t)s1 * 16 + lane];
    v4u v2 = xv[(size_t)s2 * 16 + lane];
    v4u v3 = xv[(size_t)s3 * 16 + lane];
    a0.x += h2f(v0.x); a0.y += h2f(v0.y); a0.z += h2f(v0.z); a0.w += h2f(v0.w);
    a1.x += h2f(v1.x); a1.y += h2f(v1.y); a1.z += h2f(v1.z); a1.w += h2f(v1.w);
    a2.x += h2f(v2.x); a2.y += h2f(v2.y); a2.z += h2f(v2.z); a2.w += h2f(v2.w);
    a3.x += h2f(v3.x); a3.y += h2f(v3.y); a3.z += h2f(v3.z); a3.w += h2f(v3.w);
  }
  for (; i < d; ++i) {
    int s = eidx[start + i];
    v4u v = xv[(size_t)s * 16 + lane];
    a0.x += h2f(v.x); a0.y += h2f(v.y); a0.z += h2f(v.z); a0.w += h2f(v.w);
  }
  float inv = 1.0f / (float)(d > 0 ? d : 1);
  v4u o;
  o.x = f2h((a0.x + a1.x + a2.x + a3.x) * inv);
  o.y = f2h((a0.y + a1.y + a2.y + a3.y) * inv);
  o.z = f2h((a0.z + a1.z + a2.z + a3.z) * inv);
  o.w = f2h((a0.w + a1.w + a2.w + a3.w) * inv);
  __builtin_nontemporal_store(o, (v4u*)meanh + (size_t)node * 16 + lane);
}

// ---------------- combine via MFMA: relu(mean@Wl + x@Wr + b) ----------------
// One wave per 16-node M-tile (grid-stride). D[16x64] = A_mean[16x64]@Wl + A_x[16x64]@Wr + b.
// mfma_f32_16x16x32_f16: A[m=lane&15][k=quad*8+j], B[k=quad*8+j][n=lane&15] (pre-swizzled),
// C/D: col=lane&15, row=quad*4+reg. Epilogue: per-wave LDS staging (no block barrier —
// waves have different trip counts), line-complete stores.
__global__ __launch_bounds__(256, 4) void combine_mfma_kernel(
    const unsigned short* __restrict__ meanh, const unsigned short* __restrict__ xh,
    const unsigned short* __restrict__ wfrag,  // [2 matrices][8 frags][64 lanes][8 halfs]
    const float* __restrict__ bb, float* __restrict__ outf,
    unsigned short* __restrict__ outh) {
  __shared__ float st[4][16 * 68 + 8];
  int tid = threadIdx.x;
  int wid = tid >> 6;
  int lane = tid & 63;
  int mlo = lane & 15;
  int quad = lane >> 4;
  const v8h* wf = (const v8h*)wfrag;
  v8h BL[8], BR[8];
#pragma unroll
  for (int i = 0; i < 8; ++i) BL[i] = wf[i * 64 + lane];
#pragma unroll
  for (int i = 0; i < 8; ++i) BR[i] = wf[512 + i * 64 + lane];
  float bias[4];
#pragma unroll
  for (int t = 0; t < 4; ++t) bias[t] = bb[t * 16 + mlo];
  float* stw = st[wid];
  int gw = blockIdx.x * 4 + wid;
  int nw = CMB_BLOCKS * 4;
  for (int tile = gw; tile < NTILES; tile += nw) {
    int node0 = tile * 16;
    const _Float16* mrow = (const _Float16*)meanh + (size_t)(node0 + mlo) * HDIM + quad * 8;
    const _Float16* xrow = (const _Float16*)xh + (size_t)(node0 + mlo) * HDIM + quad * 8;
    v8h Am0 = *(const v8h*)(mrow);
    v8h Am1 = *(const v8h*)(mrow + 32);
    v8h Ax0 = *(const v8h*)(xrow);
    v8h Ax1 = *(const v8h*)(xrow + 32);
#pragma unroll
    for (int t = 0; t < 4; ++t) {
      v4f acc = {bias[t], bias[t], bias[t], bias[t]};
      acc = __builtin_amdgcn_mfma_f32_16x16x32_f16(Am0, BL[t * 2 + 0], acc, 0, 0, 0);
      acc = __builtin_amdgcn_mfma_f32_16x16x32_f16(Am1, BL[t * 2 + 1], acc, 0, 0, 0);
      acc = __builtin_amdgcn_mfma_f32_16x16x32_f16(Ax0, BR[t * 2 + 0], acc, 0, 0, 0);
      acc = __builtin_amdgcn_mfma_f32_16x16x32_f16(Ax1, BR[t * 2 + 1], acc, 0, 0, 0);
#pragma unroll
      for (int r = 0; r < 4; ++r)
        stw[(quad * 4 + r) * 68 + t * 16 + mlo] = fmaxf(acc[r], 0.f);
    }
    // wave-local LDS RAW: compiler inserts lgkmcnt waits; no barrier (per-wave region)
    int rr = lane >> 2;
    int c0 = (lane & 3) * 16;
    const float* ap = &stw[rr * 68 + c0];
    if (outh) {
      unsigned short* orow = outh + (size_t)(node0 + rr) * HDIM + c0;
#pragma unroll
      for (int g = 0; g < 4; ++g) {
        v4u o;
        o.x = f2h(ap[g * 4 + 0]); o.y = f2h(ap[g * 4 + 1]);
        o.z = f2h(ap[g * 4 + 2]); o.w = f2h(ap[g * 4 + 3]);
        *(v4u*)(orow + g * 4) = o;
      }
    } else {
      float* orow = outf + (size_t)(node0 + rr) * HDIM + c0;
#pragma unroll
      for (int g = 0; g < 4; ++g) {
        float4 o;
        o.x = ap[g * 4 + 0]; o.y = ap[g * 4 + 1];
        o.z = ap[g * 4 + 2]; o.w = ap[g * 4 + 3];
        *(float4*)(orow + g * 4) = o;
      }
    }
  }
}

// ---------------- classifier: out = relu(x@Wc1+bc1)@Wc2 + bc2  (fp32 input) ----------------
__global__ __launch_bounds__(256, 2) void classifier_kernel(
    const float* __restrict__ x, const float* __restrict__ W1, const float* __restrict__ b1,
    const float* __restrict__ W2, const float* __restrict__ b2,
    float* __restrict__ out, int n) {
  int node = blockIdx.x * 256 + threadIdx.x;
  if (node >= n) return;
  float4 row[16];
  const float4* xv = (const float4*)(x + (size_t)node * HDIM);
#pragma unroll
  for (int i = 0; i < 16; ++i) row[i] = xv[i];
  float h[32];
#pragma unroll
  for (int f = 0; f < 32; ++f) h[f] = b1[f];
#pragma unroll
  for (int k4 = 0; k4 < 16; ++k4) {
#pragma unroll
    for (int j = 0; j < 4; ++j) {
      float xs = elem4(row[k4], j);
      int k = k4 * 4 + j;
#pragma unroll
      for (int f = 0; f < 32; ++f) h[f] += xs * W1[k * 32 + f];
    }
  }
  float o0 = b2[0], o1 = b2[1];
#pragma unroll
  for (int f = 0; f < 32; ++f) {
    float hv = fmaxf(h[f], 0.f);
    o0 += hv * W2[f * 2 + 0];
    o1 += hv * W2[f * 2 + 1];
  }
  float2 o;
  o.x = o0; o.y = o1;
  *(float2*)(out + (size_t)node * 2) = o;
}

extern "C" void kernel_launch(void* const* d_in, const int* in_sizes, int n_in,
                              void* d_out, int out_size, void* d_ws, size_t ws_size,
                              hipStream_t stream) {
  const float* x_ind = (const float*)d_in[0];
  const float* x_com = (const float*)d_in[1];
  const float* x_tru = (const float*)d_in[2];
  const int*   ei    = (const int*)d_in[3];
  const float* W_ind = (const float*)d_in[4];
  const float* b_ind = (const float*)d_in[5];
  const float* W_com = (const float*)d_in[6];
  const float* b_com = (const float*)d_in[7];
  const float* W_tru = (const float*)d_in[8];
  const float* b_tru = (const float*)d_in[9];
  const float* W1l = (const float*)d_in[10];
  const float* W1r = (const float*)d_in[11];
  const float* b1  = (const float*)d_in[12];
  const float* W2l = (const float*)d_in[13];
  const float* W2r = (const float*)d_in[14];
  const float* b2  = (const float*)d_in[15];
  const float* Wc1 = (const float*)d_in[16];
  const float* bc1 = (const float*)d_in[17];
  const float* Wc2 = (const float*)d_in[18];
  const float* bc2 = (const float*)d_in[19];

  const int* srcp = ei;           // edge_index[0]
  const int* dstp = ei + NEDGE;   // edge_index[1]

  // workspace layout (~212 MB; round-1 proved >=252 MB available)
  size_t fcount = (size_t)NTOT * HDIM;
  float* xf = (float*)d_ws;                        // fp32 final features (76.8 MB)
  unsigned* packed = (unsigned*)xf;                // ALIAS: dead before xf written
  unsigned short* xh0 = (unsigned short*)(xf + fcount);   // fp16 layer-0 features
  unsigned short* xh1 = xh0 + fcount;                     // fp16 layer-1 features
  unsigned short* mnh = xh1 + fcount;                     // fp16 mean (stream)
  int* eidx    = (int*)(mnh + fcount);
  int* nodeoff = eidx + NEDGE;
  int* deg     = nodeoff + NTOT;
  int* chist   = deg + NTOT;
  int* cbase   = chist + NCB;
  int* ccur    = cbase + NCB;
  // 16B-aligned weight-fragment area (4 matrices x 4096 halfs = 32 KB)
  unsigned short* wfrag = (unsigned short*)((((size_t)(ccur + NCB)) + 15) & ~(size_t)15);
  size_t needed = (size_t)((char*)(wfrag + 4 * 4096) - (char*)d_ws) + 64;
  if (ws_size < needed) return;  // would corrupt; fail visibly instead

  (void)hipMemsetAsync(chist, 0, (size_t)NCB * sizeof(int), stream);

  // weight prep (fp16 + fragment swizzle), independent of everything else
  prep_weights_kernel<<<1, 256, 0, stream>>>(W1l, W1r, W2l, W2r, wfrag);

  // encoders (write fp16 xh0; independent of edge pipeline)
  encode_kernel<32><<<(N_IND + 255) / 256, 256, 0, stream>>>(x_ind, W_ind, b_ind, xh0, N_IND, 0);
  encode_kernel<48><<<(N_COM + 255) / 256, 256, 0, stream>>>(x_com, W_com, b_com, xh0, N_COM, N_IND);
  encode_kernel<24><<<(N_TRU + 255) / 256, 256, 0, stream>>>(x_tru, W_tru, b_tru, xh0, N_TRU, N_IND + N_COM);

  // coarse partition -> per-coarse-bucket counting sort -> node-grouped CSR
  coarse_hist_kernel<<<NCHUNKS, 256, 0, stream>>>(dstp, chist, NEDGE);
  coarse_scan_kernel<<<1, 512, 0, stream>>>(chist, cbase, ccur);
  coarse_scatter_kernel<<<NCHUNKS, 256, 0, stream>>>(srcp, dstp, ccur, packed, NEDGE);
  sort_coarse_kernel<<<NCB, 256, 0, stream>>>(packed, cbase, chist, eidx, nodeoff, deg);

  // SAGE layer 1: aggregate fp16 -> fp16 mean; MFMA combine -> fp16 x1
  aggregate_kernel<<<(NTOT * 16 + 255) / 256, 256, 0, stream>>>(xh0, nodeoff, deg, eidx, mnh, NTOT);
  combine_mfma_kernel<<<CMB_BLOCKS, 256, 0, stream>>>(mnh, xh0, wfrag, b1, nullptr, xh1);

  // SAGE layer 2: aggregate fp16 -> fp16 mean; MFMA combine -> fp32 xf
  aggregate_kernel<<<(NTOT * 16 + 255) / 256, 256, 0, stream>>>(xh1, nodeoff, deg, eidx, mnh, NTOT);
  combine_mfma_kernel<<<CMB_BLOCKS, 256, 0, stream>>>(mnh, xh1, wfrag + 2 * 4096, b2, xf, nullptr);

  // classifier (fp32 input, unquantized)
  classifier_kernel<<<(NTOT + 255) / 256, 256, 0, stream>>>(xf, Wc1, bc1, Wc2, bc2,
                                                            (float*)d_out, NTOT);
}